// Round 7
// baseline (4733.640 us; speedup 1.0000x reference)
//
#include <hip/hip_runtime.h>
#include <math.h>

// LSTM anomaly scan, B=256 T=1024 I=8 H=164 O=1, WL=0, THRESH=0.1.
// One block per batch element; 256 threads = 4 waves = 1 wave/SIMD =
// 1 block/CU (full 512-reg unified budget/wave; R6 proved residency works:
// WRITE_SIZE dropped to output-only with VGPR_Count at the 256 arch cap +
// AGPR overflow).
// R7 attacks the remaining gap vs the ~600us issue bound, which R6's
// counters attribute to exposed latency at 1 wave/SIMD:
//  1. tail-row weights (w2, LDS plane-major) are consumed through a DEPTH-4
//     software-pipeline ring (~136 cyc load->use distance >= ~120 cyc LDS
//     latency) instead of same-iteration use.
//  2. W_ih plane values are t-invariant -> hoisted into permanent registers
//     (R6 re-read them from LDS every step on the critical path).
//  3. gates LDS buffer is interleaved by unit [u*4+{i,f,g,o}] so the
//     post-barrier cell update is 3 ds_read_b128 instead of 12 ds_read_b32.
// Thread t owns gate rows t and 256+t in VGPRs (82 float4); rows 512..655
// are LDS plane-major, 36 per wave (lanes 0..35). Each of the 164
// v_readlane h-broadcasts feeds 3 FMAs. One barrier per step; cell/h update
// redundant per wave; pred via DPP wave reduction (deterministic).

namespace {
constexpr int kB = 256;
constexpr int kT = 1024;
constexpr int kI = 8;
constexpr int kH = 164;
constexpr int kG = 4 * kH;                 // 656
constexpr int kThreads = 256;              // 4 waves, 1 wave/SIMD
constexpr int kHC = kH / 4;                // 41 float4 planes per row
constexpr int kW2 = kG - 2 * kThreads;     // 144 third rows (512..655)
constexpr int kPerWave = kW2 / 4;          // 36 third rows per wave
constexpr int kPF = 4;                     // w2 prefetch ring depth
constexpr float kThresh = 0.1f;

__device__ __forceinline__ float rlane(float v, int l) {
    return __int_as_float(__builtin_amdgcn_readlane(__float_as_int(v), l));
}
__device__ __forceinline__ float hb(float h0, float h1, float h2, int k) {
    return (k < 64) ? rlane(h0, k)
         : (k < 128) ? rlane(h1, k - 64)
                     : rlane(h2, k - 128);
}
template <int CTRL>
__device__ __forceinline__ float dpp_add(float x) {
    int t = __builtin_amdgcn_update_dpp(0, __float_as_int(x), CTRL, 0xf, 0xf, true);
    return __int_as_float(t);
}
__device__ __forceinline__ float wave_sum(float x) {
    x += dpp_add<0x111>(x);   // row_shr:1
    x += dpp_add<0x112>(x);   // row_shr:2
    x += dpp_add<0x114>(x);   // row_shr:4
    x += dpp_add<0x118>(x);   // row_shr:8
    x += dpp_add<0x142>(x);   // row_bcast:15
    x += dpp_add<0x143>(x);   // row_bcast:31
    return rlane(x, 63);
}
__device__ __forceinline__ float sigm(float x) {
    return 1.0f / (1.0f + __expf(-x));
}
__device__ __forceinline__ float tanh_f(float x) {
    x = fminf(fmaxf(x, -15.0f), 15.0f);
    float e = __expf(2.0f * x);
    return (e - 1.0f) / (e + 1.0f);
}
// row -> (unit, gate index) in the interleaved gates layout
__device__ __forceinline__ int gate_slot(int r) {
    int g = (r >= 3 * kH) ? 3 : (r >= 2 * kH) ? 2 : (r >= kH) ? 1 : 0;
    int u = r - g * kH;
    return u * 4 + g;
}
} // namespace

__global__
__attribute__((amdgpu_flat_work_group_size(kThreads, kThreads),
               amdgpu_waves_per_eu(1, 1)))
void lstm_anom_kernel(
    const float* __restrict__ x,     // (B,T,I)
    const float* __restrict__ Wih,   // (4H,I)
    const float* __restrict__ Whh,   // (4H,H)
    const float* __restrict__ bih,   // (4H)
    const float* __restrict__ bhh,   // (4H)
    const float* __restrict__ Wout,  // (1,H)
    const float* __restrict__ bout,  // (1)
    float* __restrict__ out)         // preds (B,T) then flags (B,T)
{
    __shared__ float4 w2[kHC * kW2];        // 94,464 B (plane-major [c][row])
    __shared__ float4 gates4[2][kH];        //  5,248 B (interleaved u*4+gate)

    const int tid  = threadIdx.x;
    const int lane = tid & 63;
    const int wav  = tid >> 6;              // 0..3
    const int b    = blockIdx.x;

    // ---- one-time LDS staging (tail rows, plane-major) ----
    for (int i = tid; i < kHC * kW2; i += kThreads) {
        int c = i / kW2, r = i - c * kW2;
        w2[i] = ((const float4*)(Whh + (size_t)(2 * kThreads + r) * kH))[c];
    }

    // ---- two primary rows into VGPRs (82 float4 = 328 regs) ----
    const int r0 = tid;
    const int r1 = kThreads + tid;
    float4 wreg0[kHC], wreg1[kHC];
    {
        const float4* wr0 = (const float4*)(Whh + (size_t)r0 * kH);
        const float4* wr1 = (const float4*)(Whh + (size_t)r1 * kH);
        #pragma unroll
        for (int k = 0; k < kHC; ++k) wreg0[k] = wr0[k];
        #pragma unroll
        for (int k = 0; k < kHC; ++k) wreg1[k] = wr1[k];
    }

    // third row: 36 per wave, lanes 0..35 active (clamped for the rest)
    const int  li3   = (lane < kPerWave) ? lane : (kPerWave - 1);
    const int  i3    = wav * kPerWave + li3;        // 0..143
    const int  r3    = 2 * kThreads + i3;           // 512..655
    const bool act3  = (lane < kPerWave);

    // t-invariant W_ih planes, PERMANENT registers (R6 re-read these from
    // LDS every step)
    float4 p00 = ((const float4*)(Wih + (size_t)r0 * kI))[0];
    float4 p01 = ((const float4*)(Wih + (size_t)r0 * kI))[1];
    float4 p10 = ((const float4*)(Wih + (size_t)r1 * kI))[0];
    float4 p11 = ((const float4*)(Wih + (size_t)r1 * kI))[1];
    float4 p30 = ((const float4*)(Wih + (size_t)r3 * kI))[0];
    float4 p31 = ((const float4*)(Wih + (size_t)r3 * kI))[1];

    const float bsum0 = bih[r0] + bhh[r0];
    const float bsum1 = bih[r1] + bhh[r1];
    const float bsum3 = bih[r3] + bhh[r3];
    const bool  tanh1 = (r1 >= 2 * kH) && (r1 < 3 * kH);
    const int   s0 = gate_slot(r0);
    const int   s1 = gate_slot(r1);
    const int   s3 = gate_slot(r3);

    const int   u2  = (lane < kH - 128) ? (128 + lane) : (kH - 1);
    const float wo0 = Wout[lane];
    const float wo1 = Wout[64 + lane];
    const float wo2 = (128 + lane < kH) ? Wout[128 + lane] : 0.0f;
    const float bo  = bout[0];

    float vc0 = 0.f, vc1 = 0.f, vc2 = 0.f;
    float vh0 = 0.f, vh1 = 0.f, vh2 = 0.f;
    float pred = 0.f;

    float* pred_out = out + (size_t)b * kT;
    float* flag_out = out + (size_t)kB * kT + (size_t)b * kT;
    const float* xb = x + (size_t)b * kT * kI;

    float4 xa = ((const float4*)xb)[0];
    float4 xc = ((const float4*)xb)[1];

    __syncthreads();

    for (int t = 0; t < kT; ++t) {
        // prefetch x[t+1] (global; consumed next iter)
        const float4* nx = (const float4*)(xb + (t + 1 < kT ? (t + 1) : t) * kI);
        float4 na = nx[0];
        float4 nc = nx[1];

        const bool  anom = (t > 0) && (fabsf(pred - xa.x) > kThresh);
        const float x0e  = anom ? pred : xa.x;

        // ---- W_ih parts (all-register) ----
        float a0 = fmaf(x0e,  p00.x, bsum0);
        float a1 = xa.y * p00.y;
        float a2 = xa.z * p00.z;
        float a3 = xa.w * p00.w;
        a0 = fmaf(xc.x, p01.x, a0);
        a1 = fmaf(xc.y, p01.y, a1);
        a2 = fmaf(xc.z, p01.z, a2);
        a3 = fmaf(xc.w, p01.w, a3);
        float b0 = fmaf(x0e,  p10.x, bsum1);
        float b1 = xa.y * p10.y;
        float b2 = xa.z * p10.z;
        float b3 = xa.w * p10.w;
        b0 = fmaf(xc.x, p11.x, b0);
        b1 = fmaf(xc.y, p11.y, b1);
        b2 = fmaf(xc.z, p11.z, b2);
        b3 = fmaf(xc.w, p11.w, b3);
        float d0 = fmaf(x0e,  p30.x, bsum3);
        float d1 = xa.y * p30.y;
        float d2 = xa.z * p30.z;
        float d3 = xa.w * p30.w;
        d0 = fmaf(xc.x, p31.x, d0);
        d1 = fmaf(xc.y, p31.y, d1);
        d2 = fmaf(xc.z, p31.z, d2);
        d3 = fmaf(xc.w, p31.w, d3);

        // ---- k-loop with depth-4 prefetch ring for w2 ----
        float4 ring[kPF];
        #pragma unroll
        for (int i = 0; i < kPF; ++i) ring[i] = w2[i * kW2 + i3];

        #pragma unroll
        for (int kk = 0; kk < kHC; ++kk) {
            const int k = kk * 4;
            float4 w3 = ring[kk & (kPF - 1)];
            if (kk + kPF < kHC) ring[kk & (kPF - 1)] = w2[(kk + kPF) * kW2 + i3];
            float4 w0 = wreg0[kk];
            float4 w1 = wreg1[kk];
            float h0v = hb(vh0, vh1, vh2, k + 0);
            float h1v = hb(vh0, vh1, vh2, k + 1);
            float h2v = hb(vh0, vh1, vh2, k + 2);
            float h3v = hb(vh0, vh1, vh2, k + 3);
            a0 = fmaf(h0v, w0.x, a0);  b0 = fmaf(h0v, w1.x, b0);  d0 = fmaf(h0v, w3.x, d0);
            a1 = fmaf(h1v, w0.y, a1);  b1 = fmaf(h1v, w1.y, b1);  d1 = fmaf(h1v, w3.y, d1);
            a2 = fmaf(h2v, w0.z, a2);  b2 = fmaf(h2v, w1.z, b2);  d2 = fmaf(h2v, w3.z, d2);
            a3 = fmaf(h3v, w0.w, a3);  b3 = fmaf(h3v, w1.w, b3);  d3 = fmaf(h3v, w3.w, d3);
        }

        const float acc0 = (a0 + a1) + (a2 + a3);
        const float acc1 = (b0 + b1) + (b2 + b3);
        const float acc3 = (d0 + d1) + (d2 + d3);

        const float g0 = sigm(acc0);                       // rows 0..255: i/f
        const float g1 = tanh1 ? tanh_f(acc1) : sigm(acc1);
        const float g3 = sigm(acc3);                       // o-gate tail

        float* gw = (float*)&gates4[t & 1][0];
        gw[s0] = g0;
        gw[s1] = g1;
        if (act3) gw[s3] = g3;
        __syncthreads();

        // ---- redundant cell/h update: 3 vectorized ifgo reads ----
        const float4* gb = &gates4[t & 1][0];
        float4 q0 = gb[lane];        // (i,f,g,o) of unit lane
        float4 q1 = gb[64 + lane];
        float4 q2 = gb[u2];
        vc0 = fmaf(q0.y, vc0, q0.x * q0.z);  vh0 = q0.w * tanh_f(vc0);
        vc1 = fmaf(q1.y, vc1, q1.x * q1.z);  vh1 = q1.w * tanh_f(vc1);
        vc2 = fmaf(q2.y, vc2, q2.x * q2.z);  vh2 = q2.w * tanh_f(vc2);

        // ---- pred (identical in every wave; DPP reduce) ----
        float p = fmaf(vh0, wo0, fmaf(vh1, wo1, vh2 * wo2));
        pred = wave_sum(p) + bo;

        if (tid == 0) {
            pred_out[t] = pred;
            flag_out[t] = anom ? 1.0f : 0.0f;
        }
        xa = na;
        xc = nc;
    }
}

extern "C" void kernel_launch(void* const* d_in, const int* in_sizes, int n_in,
                              void* d_out, int out_size, void* d_ws, size_t ws_size,
                              hipStream_t stream) {
    const float* x    = (const float*)d_in[0];
    const float* Wih  = (const float*)d_in[1];
    const float* Whh  = (const float*)d_in[2];
    const float* bih  = (const float*)d_in[3];
    const float* bhh  = (const float*)d_in[4];
    const float* Wout = (const float*)d_in[5];
    const float* bout = (const float*)d_in[6];
    lstm_anom_kernel<<<dim3(kB), dim3(kThreads), 0, stream>>>(
        x, Wih, Whh, bih, bhh, Wout, bout, (float*)d_out);
}